// Round 16
// baseline (176.339 us; speedup 1.0000x reference)
//
#include <hip/hip_runtime.h>
#include <hip/hip_bf16.h>
#include <cstdint>
#include <cstddef>
#include <math.h>

// Problem constants (reference: B=4096, D=256, T=0.5)
#define BSZ   4096
#define NROW  8192          // 2*B
#define DIM   256
#define INV_T 2.0f
#define EPS_N 1e-8f
#define NTILE 2080
#define NFIN  64            // last NFIN ticket-holders run finalize chunks

typedef __attribute__((ext_vector_type(4))) float f32x4;

// async global->LDS 16B helper (wave-uniform LDS base + lane*16 layout)
__device__ __forceinline__ void load_lds16(const void* g, void* l) {
    __builtin_amdgcn_global_load_lds(
        (const __attribute__((address_space(1))) void*)g,
        (__attribute__((address_space(3))) void*)l,
        16, 0, 0);
}

#define VMWAIT(N) asm volatile("s_waitcnt vmcnt(" #N ")" ::: "memory")

// ---------------------------------------------------------------------------
// zn3 staged layout (R11/R13-verified fp8 e4m3):
//   [strip(64)][kc(4)][row(128)][slot8(8)], 8-byte units, XOR swizzle baked:
//   zn3[s][kc][row][u] holds elements kc*64 + (u^(row&7))*8 .. +8
//
// Kernel 1: row-normalize concat(z1,z2) into fp8 zn3 (R11-verified).
// Also resets the two ticket counters.
__global__ __launch_bounds__(256)
void nt_normalize(const float* __restrict__ z1,
                  const float* __restrict__ z2,
                  char* __restrict__ zn3,
                  unsigned int* __restrict__ cnt) {
    const int wave = threadIdx.x >> 6;
    const int lane = threadIdx.x & 63;
    const int row  = blockIdx.x * 4 + wave;
    const float* src = (row < BSZ) ? (z1 + (size_t)row * DIM)
                                   : (z2 + (size_t)(row - BSZ) * DIM);
    const float4 v = ((const float4*)src)[lane];
    float ss = v.x * v.x + v.y * v.y + v.z * v.z + v.w * v.w;
    #pragma unroll
    for (int off = 32; off; off >>= 1) ss += __shfl_xor(ss, off);
    const float rinv = 1.0f / fmaxf(sqrtf(ss), EPS_N);  // torch eps clamp
    int pk = 0;
    pk = __builtin_amdgcn_cvt_pk_fp8_f32(v.x * rinv, v.y * rinv, pk, false);
    pk = __builtin_amdgcn_cvt_pk_fp8_f32(v.z * rinv, v.w * rinv, pk, true);
    // lane i holds elements k = 4i..4i+3: kc=i>>4, slot8=(i>>1)&7, off=(i&1)*4
    const int s    = row >> 7;
    const int lrow = row & 127;
    const int kc   = lane >> 4;
    const int unit = (lane >> 1) & 7;
    const int off4 = (lane & 1) * 4;
    const int u    = unit ^ (lrow & 7);          // baked swizzle
    *(int*)(zn3 + (size_t)s * 32768 + kc * 8192 + lrow * 64 + u * 8 + off4) = pk;
    if (row == 0 && lane == 0) { cnt[0] = 0u; cnt[1] = 0u; }
}

// ---------------------------------------------------------------------------
// Kernel 2: tiled Zn·Znᵀ (R14-verbatim compute: fp8, 128x128 tiles, 2080
// blocks, 4 waves, counted-vmcnt dbuf, private-slot epilogue) + FUSED
// FINALIZE: after the epilogue every block takes a completion ticket
// (threadfence + atomicAdd). The last NFIN ticket-holders — which are in
// the grid's drain tail, on otherwise-idle CUs — spin until cnt==NTILE,
// then each reduces a 128-row chunk of part[8192][128] using agent-scope
// (L2-bypassing) loads, and a second ticket elects the folder of the 64
// block sums. Saves the separate nt_finalize dispatch; the finalize work
// hides in the tail. All shared scratch aliases the dead lds buffer so
// LDS_Block_Size stays 32768 (5 blocks/CU).
__global__ __launch_bounds__(256)
void nt_gram(const char* __restrict__ zn3,
             float* __restrict__ part,
             float* __restrict__ pos,
             float* __restrict__ blocksum,
             unsigned int* __restrict__ cnt,
             float* __restrict__ out) {
    // Triangular decode: S(bi) = 64*bi - bi*(bi-1)/2 tiles before row bi.
    const int l = blockIdx.x;
    int bi = (int)((129.0 - sqrt(16641.0 - 8.0 * (double)l)) * 0.5);
    while (64 * (bi + 1) - (bi + 1) * bi / 2 <= l) ++bi;   // fp-edge correction
    while (64 * bi - bi * (bi - 1) / 2 > l) --bi;
    const int bj = bi + (l - (64 * bi - bi * (bi - 1) / 2));

    __shared__ char lds[32768];   // buf0 | buf1; each: As 8 KB | Bs 8 KB

    const int t    = threadIdx.x;
    const int lane = t & 63;
    const int wave = t >> 6;
    const int wrow = (wave >> 1) * 64;
    const int wcol = (wave & 1) * 64;
    const int q    = lane >> 4;
    const int r16  = lane & 15;
    const int sw   = r16 & 7;                    // swizzle key (== row&7)
    const int t16  = t * 16;

    const char* A2 = zn3 + (size_t)bi * 32768;
    const char* B2 = zn3 + (size_t)bj * 32768;

    f32x4 acc[4][4] = {};

#define STAGE(kc, buf)                                                   \
    {                                                                    \
        char* d_ = lds + (buf) * 16384;                                  \
        load_lds16(A2 + (kc) * 8192 + t16,        d_ + t16);             \
        load_lds16(A2 + (kc) * 8192 + 4096 + t16, d_ + 4096 + t16);      \
        load_lds16(B2 + (kc) * 8192 + t16,        d_ + 8192 + t16);      \
        load_lds16(B2 + (kc) * 8192 + 4096 + t16, d_ + 12288 + t16);     \
    }

#define COMPUTE(buf)                                                     \
    {                                                                    \
        const char* As_ = lds + (buf) * 16384;                           \
        const char* Bs_ = As_ + 8192;                                    \
        _Pragma("unroll")                                                \
        for (int kh = 0; kh < 2; ++kh) {                                 \
            const int spos = (((kh << 2) + q) ^ sw) << 3;                \
            long af[4], bfv[4];                                          \
            _Pragma("unroll")                                            \
            for (int mi = 0; mi < 4; ++mi)                               \
                af[mi] = *(const long*)(As_ + (wrow + mi * 16 + r16) * 64 + spos); \
            _Pragma("unroll")                                            \
            for (int ni = 0; ni < 4; ++ni)                               \
                bfv[ni] = *(const long*)(Bs_ + (wcol + ni * 16 + r16) * 64 + spos); \
            _Pragma("unroll")                                            \
            for (int mi = 0; mi < 4; ++mi)                               \
                _Pragma("unroll")                                        \
                for (int ni = 0; ni < 4; ++ni)                           \
                    acc[mi][ni] = __builtin_amdgcn_mfma_f32_16x16x32_fp8_fp8( \
                        af[mi], bfv[ni], acc[mi][ni], 0, 0, 0);          \
        }                                                                \
    }

    // R14's proven ledger: 4,8 -> wait4 -> 8 -> wait4 -> 8 -> wait4 -> wait0.
    STAGE(0, 0)
    STAGE(1, 1)
    VMWAIT(4);
    __builtin_amdgcn_s_barrier();
    COMPUTE(0)
    __builtin_amdgcn_s_barrier();
    __builtin_amdgcn_sched_barrier(0);
    STAGE(2, 0)
    VMWAIT(4);
    __builtin_amdgcn_s_barrier();
    COMPUTE(1)
    __builtin_amdgcn_s_barrier();
    __builtin_amdgcn_sched_barrier(0);
    STAGE(3, 1)
    VMWAIT(4);
    __builtin_amdgcn_s_barrier();
    COMPUTE(0)
    VMWAIT(0);
    __builtin_amdgcn_s_barrier();
    COMPUTE(1)
#undef STAGE
#undef COMPUTE

    // Epilogue (R13/R14-verified). C/D: col=lane&15, row=(lane>>4)*4+reg.
    const int c = r16;
    const bool diag_block = (bi == bj);
    const int rslot = 2 * bj + (wcol >> 6);      // row-side private slot
    const int cslot = 2 * bi + (wrow >> 6);      // col-side private slot
    float colp[4] = {0.f, 0.f, 0.f, 0.f};

    #pragma unroll
    for (int mi = 0; mi < 4; ++mi) {
        #pragma unroll
        for (int r = 0; r < 4; ++r) {
            const int grow = bi * 128 + wrow + mi * 16 + q * 4 + r;
            float s = 0.f;
            #pragma unroll
            for (int ni = 0; ni < 4; ++ni) {
                const int gcol = bj * 128 + wcol + ni * 16 + c;
                const float val = acc[mi][ni][r];
                float e = __expf(val * INV_T);
                e = (grow == gcol) ? 0.f : e;   // exact diagonal exclusion
                s += e;
                colp[ni] += e;
                if (gcol == grow + BSZ) {       // positive pair (bj == bi+32)
                    pos[grow] = val;
                    pos[gcol] = val;            // symmetric partner
                }
            }
            s += __shfl_xor(s, 1);
            s += __shfl_xor(s, 2);
            s += __shfl_xor(s, 4);
            s += __shfl_xor(s, 8);
            if (c == 0) part[(size_t)grow * 128 + rslot] = s;
        }
    }
    if (!diag_block) {
        #pragma unroll
        for (int ni = 0; ni < 4; ++ni) {
            float cs = colp[ni];
            cs += __shfl_xor(cs, 16);
            cs += __shfl_xor(cs, 32);          // butterfly: wave total everywhere
            if (q == 0)
                part[(size_t)(bj * 128 + wcol + ni * 16 + c) * 128 + cslot] = cs;
        }
    }

    // ---- Fused finalize (ticket; last NFIN blocks = grid drain tail) ----
    unsigned int* ltk = (unsigned int*)lds;      // alias dead LDS
    float*        r4  = (float*)lds + 16;
    int*          win = (int*)lds + 24;
    __syncthreads();                             // all waves done with lds
    if (t == 0) {
        __threadfence();                         // release part/pos writes
        ltk[0] = atomicAdd(&cnt[0], 1u);
    }
    __syncthreads();
    const unsigned int ticket = ltk[0];
    if (ticket >= NTILE - NFIN) {
        const int chunk = (int)ticket - (NTILE - NFIN);
        if (t == 0) {
            while (__hip_atomic_load(&cnt[0], __ATOMIC_ACQUIRE,
                                     __HIP_MEMORY_SCOPE_AGENT) < NTILE)
                __builtin_amdgcn_s_sleep(4);
        }
        __syncthreads();
        // Reduce rows chunk*128..+127 of part with agent-scope (coherent) loads.
        const int row  = chunk * 128 + (t >> 1);
        const int half = t & 1;
        const unsigned long long* p8 =
            (const unsigned long long*)(part + (size_t)row * 128 + half * 64);
        float s = 0.f;
        #pragma unroll
        for (int j2 = 0; j2 < 32; ++j2) {
            const unsigned long long w = __hip_atomic_load(
                &p8[j2], __ATOMIC_RELAXED, __HIP_MEMORY_SCOPE_AGENT);
            const float2 f2 = __builtin_bit_cast(float2, w);
            s += f2.x + f2.y;
        }
        s += __shfl_xor(s, 1);                  // combine the two halves
        float contrib = 0.f;
        if (half == 0) {
            const float pv = __hip_atomic_load(
                &pos[row], __ATOMIC_RELAXED, __HIP_MEMORY_SCOPE_AGENT);
            const float pl = pv * INV_T;
            contrib = logf(__expf(pl) + s) - pl;
        }
        #pragma unroll
        for (int off = 32; off; off >>= 1) contrib += __shfl_xor(contrib, off);
        if (lane == 0) r4[wave] = contrib;
        __syncthreads();
        if (t == 0) {
            blocksum[chunk] = r4[0] + r4[1] + r4[2] + r4[3];
            __threadfence();
            win[0] = (atomicAdd(&cnt[1], 1u) == NFIN - 1u);
        }
        __syncthreads();
        if (win[0] && t < 64) {                 // elected folder
            float v = __hip_atomic_load(&blocksum[t], __ATOMIC_RELAXED,
                                        __HIP_MEMORY_SCOPE_AGENT);
            #pragma unroll
            for (int off = 32; off; off >>= 1) v += __shfl_xor(v, off);
            if (t == 0) out[0] = v * (1.0f / NROW);
        }
    }
}

// ---------------------------------------------------------------------------
extern "C" void kernel_launch(void* const* d_in, const int* in_sizes, int n_in,
                              void* d_out, int out_size, void* d_ws, size_t ws_size,
                              hipStream_t stream) {
    const float* z1 = (const float*)d_in[0];
    const float* z2 = (const float*)d_in[1];
    float* out = (float*)d_out;

    // Workspace (~6.03 MB of the 256 MiB ws):
    char*  zn3      = (char*)d_ws;                                   // 2 MB
    float* part     = (float*)((char*)d_ws + (size_t)2097152);       // 4 MB
    float* pos      = (float*)((char*)d_ws + (size_t)6291456);       // 32 KB
    float* blocksum = pos + NROW;                                    // 256 B
    unsigned int* cnt = (unsigned int*)(blocksum + 64);              // 8 B

    nt_normalize<<<NROW / 4, 256, 0, stream>>>(z1, z2, zn3, cnt);
    nt_gram<<<NTILE, 256, 0, stream>>>(zn3, part, pos, blocksum, cnt, out);
}

// Round 17
// 95.489 us; speedup vs baseline: 1.8467x; 1.8467x over previous
//
#include <hip/hip_runtime.h>
#include <hip/hip_bf16.h>
#include <cstdint>
#include <cstddef>
#include <math.h>

// Problem constants (reference: B=4096, D=256, T=0.5)
#define BSZ   4096
#define NROW  8192          // 2*B
#define DIM   256
#define INV_T 2.0f
#define EPS_N 1e-8f

typedef __attribute__((ext_vector_type(4))) float f32x4;

// async global->LDS 16B helper (wave-uniform LDS base + lane*16 layout)
__device__ __forceinline__ void load_lds16(const void* g, void* l) {
    __builtin_amdgcn_global_load_lds(
        (const __attribute__((address_space(1))) void*)g,
        (__attribute__((address_space(3))) void*)l,
        16, 0, 0);
}

#define VMWAIT(N) asm volatile("s_waitcnt vmcnt(" #N ")" ::: "memory")

// ---------------------------------------------------------------------------
// zn3 staged layout (R11/R13-verified fp8 e4m3):
//   [strip(64)][kc(4)][row(128)][slot8(8)], 8-byte units, XOR swizzle baked:
//   zn3[s][kc][row][u] holds elements kc*64 + (u^(row&7))*8 .. +8
//
// Kernel 1: row-normalize concat(z1,z2) into fp8 zn3 (R11-verified).
// Also resets the finalize ticket counter.
__global__ __launch_bounds__(256)
void nt_normalize(const float* __restrict__ z1,
                  const float* __restrict__ z2,
                  char* __restrict__ zn3,
                  unsigned int* __restrict__ cnt) {
    const int wave = threadIdx.x >> 6;
    const int lane = threadIdx.x & 63;
    const int row  = blockIdx.x * 4 + wave;
    const float* src = (row < BSZ) ? (z1 + (size_t)row * DIM)
                                   : (z2 + (size_t)(row - BSZ) * DIM);
    const float4 v = ((const float4*)src)[lane];
    float ss = v.x * v.x + v.y * v.y + v.z * v.z + v.w * v.w;
    #pragma unroll
    for (int off = 32; off; off >>= 1) ss += __shfl_xor(ss, off);
    const float rinv = 1.0f / fmaxf(sqrtf(ss), EPS_N);  // torch eps clamp
    int pk = 0;
    pk = __builtin_amdgcn_cvt_pk_fp8_f32(v.x * rinv, v.y * rinv, pk, false);
    pk = __builtin_amdgcn_cvt_pk_fp8_f32(v.z * rinv, v.w * rinv, pk, true);
    // lane i holds elements k = 4i..4i+3: kc=i>>4, slot8=(i>>1)&7, off=(i&1)*4
    const int s    = row >> 7;
    const int lrow = row & 127;
    const int kc   = lane >> 4;
    const int unit = (lane >> 1) & 7;
    const int off4 = (lane & 1) * 4;
    const int u    = unit ^ (lrow & 7);          // baked swizzle
    *(int*)(zn3 + (size_t)s * 32768 + kc * 8192 + lrow * 64 + u * 8 + off4) = pk;
    if (row == 0 && lane == 0) *cnt = 0;         // reset finalize ticket
}

// ---------------------------------------------------------------------------
// Kernel 2: tiled Zn·Znᵀ, upper triangle (2080 blocks), 128x128 tiles, 256
// threads = 4 waves (2x2 of 64x64 wave-tiles). fp8 staging/compute with
// counted-vmcnt double-buffer (R14, best-measured: 94.65 us total).
// Epilogue: private-slot stores, zero global atomics (R13-verified).
__global__ __launch_bounds__(256)
void nt_gram(const char* __restrict__ zn3,
             float* __restrict__ part,
             float* __restrict__ pos) {
    // Triangular decode: S(bi) = 64*bi - bi*(bi-1)/2 tiles before row bi.
    const int l = blockIdx.x;
    int bi = (int)((129.0 - sqrt(16641.0 - 8.0 * (double)l)) * 0.5);
    while (64 * (bi + 1) - (bi + 1) * bi / 2 <= l) ++bi;   // fp-edge correction
    while (64 * bi - bi * (bi - 1) / 2 > l) --bi;
    const int bj = bi + (l - (64 * bi - bi * (bi - 1) / 2));

    __shared__ char lds[32768];   // buf0 | buf1; each: As 8 KB | Bs 8 KB

    const int t    = threadIdx.x;
    const int lane = t & 63;
    const int wave = t >> 6;
    const int wrow = (wave >> 1) * 64;
    const int wcol = (wave & 1) * 64;
    const int q    = lane >> 4;
    const int r16  = lane & 15;
    const int sw   = r16 & 7;                    // swizzle key (== row&7)
    const int t16  = t * 16;

    const char* A2 = zn3 + (size_t)bi * 32768;
    const char* B2 = zn3 + (size_t)bj * 32768;

    f32x4 acc[4][4] = {};

    // Stage kc into buf: 4 DMA loads/thread (A: 2x4KB lines, B: 2x4KB).
#define STAGE(kc, buf)                                                   \
    {                                                                    \
        char* d_ = lds + (buf) * 16384;                                  \
        load_lds16(A2 + (kc) * 8192 + t16,        d_ + t16);             \
        load_lds16(A2 + (kc) * 8192 + 4096 + t16, d_ + 4096 + t16);      \
        load_lds16(B2 + (kc) * 8192 + t16,        d_ + 8192 + t16);      \
        load_lds16(B2 + (kc) * 8192 + 4096 + t16, d_ + 12288 + t16);     \
    }

#define COMPUTE(buf)                                                     \
    {                                                                    \
        const char* As_ = lds + (buf) * 16384;                           \
        const char* Bs_ = As_ + 8192;                                    \
        _Pragma("unroll")                                                \
        for (int kh = 0; kh < 2; ++kh) {                                 \
            const int spos = (((kh << 2) + q) ^ sw) << 3;                \
            long af[4], bfv[4];                                          \
            _Pragma("unroll")                                            \
            for (int mi = 0; mi < 4; ++mi)                               \
                af[mi] = *(const long*)(As_ + (wrow + mi * 16 + r16) * 64 + spos); \
            _Pragma("unroll")                                            \
            for (int ni = 0; ni < 4; ++ni)                               \
                bfv[ni] = *(const long*)(Bs_ + (wcol + ni * 16 + r16) * 64 + spos); \
            _Pragma("unroll")                                            \
            for (int mi = 0; mi < 4; ++mi)                               \
                _Pragma("unroll")                                        \
                for (int ni = 0; ni < 4; ++ni)                           \
                    acc[mi][ni] = __builtin_amdgcn_mfma_f32_16x16x32_fp8_fp8( \
                        af[mi], bfv[ni], acc[mi][ni], 0, 0, 0);          \
        }                                                                \
    }

    // Ledger (per-wave outstanding DMA): 4,8 -> wait4 -> 8 -> wait4 -> 8
    // -> wait4 -> wait0. Counted waits keep one stage in flight across
    // every compute; no mid-loop drain.
    STAGE(0, 0)
    STAGE(1, 1)
    VMWAIT(4);
    __builtin_amdgcn_s_barrier();
    COMPUTE(0)
    __builtin_amdgcn_s_barrier();            // all waves done reading buf0
    __builtin_amdgcn_sched_barrier(0);
    STAGE(2, 0)
    VMWAIT(4);
    __builtin_amdgcn_s_barrier();
    COMPUTE(1)
    __builtin_amdgcn_s_barrier();            // all waves done reading buf1
    __builtin_amdgcn_sched_barrier(0);
    STAGE(3, 1)
    VMWAIT(4);
    __builtin_amdgcn_s_barrier();
    COMPUTE(0)
    VMWAIT(0);
    __builtin_amdgcn_s_barrier();
    COMPUTE(1)
#undef STAGE
#undef COMPUTE

    // Epilogue (R13-verified). C/D layout: col=lane&15, row=(lane>>4)*4+reg.
    const int c = r16;
    const bool diag_block = (bi == bj);
    const int rslot = 2 * bj + (wcol >> 6);      // row-side private slot
    const int cslot = 2 * bi + (wrow >> 6);      // col-side private slot
    float colp[4] = {0.f, 0.f, 0.f, 0.f};

    #pragma unroll
    for (int mi = 0; mi < 4; ++mi) {
        #pragma unroll
        for (int r = 0; r < 4; ++r) {
            const int grow = bi * 128 + wrow + mi * 16 + q * 4 + r;
            float s = 0.f;
            #pragma unroll
            for (int ni = 0; ni < 4; ++ni) {
                const int gcol = bj * 128 + wcol + ni * 16 + c;
                const float val = acc[mi][ni][r];
                float e = __expf(val * INV_T);
                e = (grow == gcol) ? 0.f : e;   // exact diagonal exclusion
                s += e;
                colp[ni] += e;
                if (gcol == grow + BSZ) {       // positive pair (bj == bi+32)
                    pos[grow] = val;
                    pos[gcol] = val;            // symmetric partner
                }
            }
            s += __shfl_xor(s, 1);
            s += __shfl_xor(s, 2);
            s += __shfl_xor(s, 4);
            s += __shfl_xor(s, 8);
            // Private half-slot: plain store, no atomic, no collision.
            if (c == 0) part[(size_t)grow * 128 + rslot] = s;
        }
    }
    // Col sums -> bj strip rows at this wave's private half-slot.
    if (!diag_block) {
        #pragma unroll
        for (int ni = 0; ni < 4; ++ni) {
            float cs = colp[ni];
            cs += __shfl_xor(cs, 16);
            cs += __shfl_xor(cs, 32);          // butterfly: wave total in all lanes
            if (q == 0)
                part[(size_t)(bj * 128 + wcol + ni * 16 + c) * 128 + cslot] = cs;
        }
    }
}

// ---------------------------------------------------------------------------
// Kernel 3: 64 blocks x 256 threads (R13-verified); block b reduces rows
// b*128..+127 of part[8192][128], per-row lse contribution, block-reduce;
// last block (ticket) folds the 64 block sums.
__global__ __launch_bounds__(256)
void nt_finalize(const float* __restrict__ part,
                 const float* __restrict__ pos,
                 float* __restrict__ blocksum,
                 unsigned int* __restrict__ cnt,
                 float* __restrict__ out) {
    const int b    = blockIdx.x;
    const int t    = threadIdx.x;
    const int lane = t & 63;
    const int row  = b * 128 + (t >> 1);
    const int half = t & 1;

    const float4* p4 = (const float4*)(part + (size_t)row * 128 + half * 64);
    float s = 0.f;
    #pragma unroll
    for (int j = 0; j < 16; ++j) {
        const float4 v = p4[j];
        s += v.x + v.y + v.z + v.w;
    }
    s += __shfl_xor(s, 1);                 // combine the two halves
    float contrib = 0.f;
    if (half == 0) {
        const float pl = pos[row] * INV_T;
        contrib = logf(__expf(pl) + s) - pl;
    }
    #pragma unroll
    for (int off = 32; off; off >>= 1) contrib += __shfl_xor(contrib, off);
    __shared__ float r4[4];
    __shared__ int   slast;
    if (lane == 0) r4[t >> 6] = contrib;
    __syncthreads();
    if (t == 0) {
        blocksum[b] = r4[0] + r4[1] + r4[2] + r4[3];
        __threadfence();
        slast = (atomicAdd(cnt, 1u) == 63u);
    }
    __syncthreads();
    if (slast && t < 64) {                 // last block: fold 64 block sums
        float v = atomicAdd(&blocksum[t], 0.0f);   // device-coherent read
        #pragma unroll
        for (int off = 32; off; off >>= 1) v += __shfl_xor(v, off);
        if (t == 0) out[0] = v * (1.0f / NROW);
    }
}

// ---------------------------------------------------------------------------
extern "C" void kernel_launch(void* const* d_in, const int* in_sizes, int n_in,
                              void* d_out, int out_size, void* d_ws, size_t ws_size,
                              hipStream_t stream) {
    const float* z1 = (const float*)d_in[0];
    const float* z2 = (const float*)d_in[1];
    float* out = (float*)d_out;

    // Workspace (~6.03 MB of the 256 MiB ws):
    char*  zn3      = (char*)d_ws;                                   // 2 MB
    float* part     = (float*)((char*)d_ws + (size_t)2097152);       // 4 MB
    float* pos      = (float*)((char*)d_ws + (size_t)6291456);       // 32 KB
    float* blocksum = pos + NROW;                                    // 256 B
    unsigned int* cnt = (unsigned int*)(blocksum + 64);              // 4 B

    nt_normalize<<<NROW / 4, 256, 0, stream>>>(z1, z2, zn3, cnt);
    nt_gram<<<2080, 256, 0, stream>>>(zn3, part, pos);
    nt_finalize<<<64, 256, 0, stream>>>(part, pos, blocksum, cnt, out);
}